// Round 1
// baseline (27.404 us; speedup 1.0000x reference)
//
#include <hip/hip_runtime.h>

// out[b,f] = x[b,f] * S where S is a scalar derived from the small parameter
// vectors. Derivation: x is real; each channel factor is a complex scalar;
// crosstalk matrix is real; only the real part survives into the softmax-
// weighted channel combine. Hence:
//   Re(factor_c) = gain_c * cos(phase_c + 0.5*D*(wl_c - mean(wl))^2) * sigmoid(aw_c)
//   S = sum_k softmax(aw)[k] * sum_c Re(factor_c) * M[c,k]

__global__ __launch_bounds__(256) void wdm_scale_kernel(
    const float* __restrict__ x,
    const float* __restrict__ gains,
    const float* __restrict__ phases,
    const float* __restrict__ aw,
    const float* __restrict__ disp,
    const float* __restrict__ ct,     // [3][3] row-major, M[c][k]
    const float* __restrict__ wl,
    float* __restrict__ out,
    long n4)                           // number of float4 elements
{
    __shared__ float sS;
    if (threadIdx.x == 0) {
        // Compute the scalar in double precision (cos of ~1e5-magnitude args).
        const double w0 = (double)wl[0], w1 = (double)wl[1], w2 = (double)wl[2];
        const double wlm = (w0 + w1 + w2) / 3.0;
        const double D = (double)disp[0];

        double a0 = (double)aw[0], a1 = (double)aw[1], a2 = (double)aw[2];
        double awm = fmax(fmax(a0, a1), a2);

        double re[3];
        double ex[3];
        double sumex = 0.0;
        for (int c = 0; c < 3; ++c) {
            double d  = (double)wl[c] - wlm;
            double ph = (double)phases[c] + 0.5 * D * d * d;
            double sg = 1.0 / (1.0 + exp(-(double)aw[c]));
            re[c] = (double)gains[c] * cos(ph) * sg;
            ex[c] = exp((double)aw[c] - awm);
            sumex += ex[c];
        }
        double S = 0.0;
        for (int k = 0; k < 3; ++k) {
            double acc = 0.0;
            for (int c = 0; c < 3; ++c) acc += re[c] * (double)ct[c * 3 + k];
            S += (ex[k] / sumex) * acc;
        }
        sS = (float)S;
    }
    __syncthreads();
    const float S = sS;

    const float4* __restrict__ x4 = (const float4*)x;
    float4* __restrict__ o4 = (float4*)out;

    long i = (long)blockIdx.x * blockDim.x + threadIdx.x;
    const long stride = (long)gridDim.x * blockDim.x;
    for (; i < n4; i += stride) {
        float4 v = x4[i];
        v.x *= S; v.y *= S; v.z *= S; v.w *= S;
        o4[i] = v;
    }
}

extern "C" void kernel_launch(void* const* d_in, const int* in_sizes, int n_in,
                              void* d_out, int out_size, void* d_ws, size_t ws_size,
                              hipStream_t stream) {
    const float* x      = (const float*)d_in[0];
    const float* gains  = (const float*)d_in[1];
    const float* phases = (const float*)d_in[2];
    const float* aw     = (const float*)d_in[3];
    const float* disp   = (const float*)d_in[4];
    const float* ct     = (const float*)d_in[5];
    const float* wl     = (const float*)d_in[6];
    float* out = (float*)d_out;

    long n = (long)in_sizes[0];          // 4096*4096, divisible by 4
    long n4 = n >> 2;

    int block = 256;
    long want = (n4 + block - 1) / block;
    int grid = (int)(want < 2048 ? want : 2048);

    wdm_scale_kernel<<<grid, block, 0, stream>>>(x, gains, phases, aw, disp,
                                                 ct, wl, out, n4);
}